// Round 2
// baseline (274.450 us; speedup 1.0000x reference)
//
#include <hip/hip_runtime.h>
#include <math.h>

namespace {

constexpr int Himg = 224, Wimg = 224, Cn = 3, Kk = 32;
constexpr int TS = 16;            // output tile side
constexpr int HALO = Kk - 1;      // 31 (pad 15 top/left, 16 bottom/right)
constexpr int TD = TS + HALO;     // 47 tile dim
constexpr int TSTRIDE = 48;       // row stride in pixels (padded)

__global__ __launch_bounds__(256)
void blur_fused(const float* __restrict__ x,
                const float* __restrict__ tbl,
                const int* __restrict__ amt,
                const int* __restrict__ ang,
                float* __restrict__ out)
{
    const int b   = blockIdx.z;
    const int tid = threadIdx.x;

    __shared__ int   s_count;
    __shared__ float s_w;
    __shared__ int   s_off[Kk * Kk];               // per-tap LDS byte offsets
    __shared__ float s_img[TD * TSTRIDE * Cn];     // zero-padded halo tile (AoS)

    if (tid == 0) { s_count = 0; s_w = 0.0f; }
    __syncthreads();

    // ---- build rotated-kernel tap list (reference-exact numerics) ----
    const int a = amt[b];
    const float rad = (float)ang[b] * (float)(M_PI / 180.0);
    const double rd  = (double)rad;
    const float  cth = (float)cos(rd);
    const float  sth = (float)sin(rd);
    const float  e   = 31.0f;
    const float xoff = __fmul_rn(__fsub_rn(e, __fsub_rn(__fmul_rn(cth, e), __fmul_rn(sth, e))), 0.5f);
    const float yoff = __fmul_rn(__fsub_rn(e, __fadd_rn(__fmul_rn(sth, e), __fmul_rn(cth, e))), 0.5f);

    for (int p = tid; p < Kk * Kk; p += 256) {
        const int   ky = p >> 5, kx = p & 31;
        const float xf = (float)kx, yf = (float)ky;
        const float sx = __fadd_rn(__fsub_rn(__fmul_rn(cth, xf), __fmul_rn(sth, yf)), xoff);
        const float sy = __fadd_rn(__fadd_rn(__fmul_rn(sth, xf), __fmul_rn(cth, yf)), yoff);
        const int ix = (int)rintf(sx);   // round-half-even == jnp.round
        const int iy = (int)rintf(sy);
        if (ix >= 0 && ix < Kk && iy >= 0 && iy < Kk) {
            const float v = tbl[((size_t)(a * Kk + iy) * Kk + ix) * Cn];
            if (v != 0.0f) {
                const int idx = atomicAdd(&s_count, 1);
                s_off[idx] = (ky * TSTRIDE + kx) * (int)(Cn * sizeof(float));
                s_w = v;                 // benign race: all writers store 1/size
            }
        }
    }

    // ---- stage zero-padded halo tile into LDS (coalesced 12B/thread) ----
    const int x0 = (blockIdx.x << 4) - 15;
    const int y0 = (blockIdx.y << 4) - 15;
    const float* xb = x + (size_t)b * (Himg * Wimg * Cn);
    for (int p = tid; p < TD * TD; p += 256) {
        const int ty = p / TD, tx = p - ty * TD;
        const int gy = y0 + ty, gx = x0 + tx;
        float v0 = 0.0f, v1 = 0.0f, v2 = 0.0f;
        if ((unsigned)gy < (unsigned)Himg && (unsigned)gx < (unsigned)Wimg) {
            const float* s = xb + ((size_t)gy * Wimg + gx) * Cn;
            v0 = s[0]; v1 = s[1]; v2 = s[2];
        }
        float* d = &s_img[(ty * TSTRIDE + tx) * Cn];
        d[0] = v0; d[1] = v1; d[2] = v2;
    }
    __syncthreads();

    const int   n = s_count;
    const float w = s_w;

    // ---- sparse tap accumulation, all from LDS, no bounds checks ----
    const int lx = tid & 15, ly = tid >> 4;
    const char* base = (const char*)&s_img[(ly * TSTRIDE + lx) * Cn];

    float a0 = 0.0f, a1 = 0.0f, a2 = 0.0f;
    for (int i = 0; i < n; ++i) {
        const float* t = (const float*)(base + s_off[i]);
        a0 += t[0]; a1 += t[1]; a2 += t[2];
    }

    const int oy = (blockIdx.y << 4) + ly;
    const int ox = (blockIdx.x << 4) + lx;
    float* o = out + ((size_t)b * Himg * Wimg + (size_t)oy * Wimg + ox) * Cn;
    o[0] = a0 * w;
    o[1] = a1 * w;
    o[2] = a2 * w;
}

}  // namespace

extern "C" void kernel_launch(void* const* d_in, const int* in_sizes, int n_in,
                              void* d_out, int out_size, void* d_ws, size_t ws_size,
                              hipStream_t stream) {
    const float* x   = (const float*)d_in[0];
    const float* tbl = (const float*)d_in[1];
    const int*   amt = (const int*)d_in[2];
    const int*   ang = (const int*)d_in[3];
    float*       out = (float*)d_out;

    const int B = in_sizes[2];  // 128
    dim3 grid(Wimg / TS, Himg / TS, B);
    blur_fused<<<grid, 256, 0, stream>>>(x, tbl, amt, ang, out);
}

// Round 3
// 232.940 us; speedup vs baseline: 1.1782x; 1.1782x over previous
//
#include <hip/hip_runtime.h>
#include <math.h>

namespace {

constexpr int Himg = 224, Wimg = 224, Cn = 3, Kk = 32;
constexpr int TILE = 32;        // output tile side (32x32 per block)
constexpr int MAXT = 64;        // max taps per image (observed ~<= size*sqrt2 <= 46)
constexpr int WSTRIDE = 256;    // ints per image in workspace

typedef float v4 __attribute__((ext_vector_type(4), aligned(4)));

// ---------------- pre-pass: one tap list per image ----------------
__global__ __launch_bounds__(64)
void build_taps(const float* __restrict__ tbl,
                const int* __restrict__ amt,
                const int* __restrict__ ang,
                int* __restrict__ ws)
{
    const int b   = blockIdx.x;
    const int tid = threadIdx.x;

    __shared__ int   s_cnt;
    __shared__ float s_w;
    __shared__ int   s_dky[MAXT], s_dkx[MAXT], s_voff[MAXT];

    if (tid == 0) { s_cnt = 0; s_w = 0.0f; }
    __syncthreads();

    const int a = amt[b];
    // reference-exact numerics (verified absmax 0.0039 in R1/R2)
    const float  rad = (float)ang[b] * (float)(M_PI / 180.0);
    const double rd  = (double)rad;
    const float  cth = (float)cos(rd);
    const float  sth = (float)sin(rd);
    const float  e   = 31.0f;
    const float xoff = __fmul_rn(__fsub_rn(e, __fsub_rn(__fmul_rn(cth, e), __fmul_rn(sth, e))), 0.5f);
    const float yoff = __fmul_rn(__fsub_rn(e, __fadd_rn(__fmul_rn(sth, e), __fmul_rn(cth, e))), 0.5f);

    for (int p = tid; p < Kk * Kk; p += 64) {
        const int   ky = p >> 5, kx = p & 31;
        const float xf = (float)kx, yf = (float)ky;
        const float sx = __fadd_rn(__fsub_rn(__fmul_rn(cth, xf), __fmul_rn(sth, yf)), xoff);
        const float sy = __fadd_rn(__fadd_rn(__fmul_rn(sth, xf), __fmul_rn(cth, yf)), yoff);
        const int ix = (int)rintf(sx);   // round-half-even == jnp.round
        const int iy = (int)rintf(sy);
        if (ix >= 0 && ix < Kk && iy >= 0 && iy < Kk) {
            const float v = tbl[((a * Kk + iy) * Kk + ix) * Cn];
            if (v != 0.0f) {
                const int idx = atomicAdd(&s_cnt, 1);
                if (idx < MAXT) {
                    s_dky[idx]  = ky - 15;
                    s_dkx[idx]  = kx - 15;
                    s_voff[idx] = ((ky - 15) * Wimg + (kx - 15)) * (int)(Cn * sizeof(float));
                    s_w = v;                 // benign race: all writers store 1/size
                }
            }
        }
    }
    __syncthreads();

    const int n = min(s_cnt, MAXT);
    int* wsb = ws + b * WSTRIDE;
    if (tid == 0) { wsb[0] = n; wsb[1] = __float_as_int(s_w); }
    for (int i = tid; i < n; i += 64) {
        wsb[2 + i]            = s_dky[i];
        wsb[2 + MAXT + i]     = s_dkx[i];
        wsb[2 + 2 * MAXT + i] = s_voff[i];
    }
}

// ---------------- conv: 4 px/thread, interior fast path ----------------
__global__ __launch_bounds__(256)
void blur_conv(const float* __restrict__ x,
               const int* __restrict__ ws,
               float* __restrict__ out)
{
    const int b   = blockIdx.z;
    const int tid = threadIdx.x;

    __shared__ int sh[2 + 3 * MAXT];
    const int* wsb = ws + b * WSTRIDE;
    if (tid < 2 + 3 * MAXT) sh[tid] = wsb[tid];
    __syncthreads();

    const int   n = sh[0];
    const float w = __int_as_float(sh[1]);
    const int* s_dky  = sh + 2;
    const int* s_dkx  = sh + 2 + MAXT;
    const int* s_voff = sh + 2 + 2 * MAXT;

    const int x0 = blockIdx.x * TILE, y0 = blockIdx.y * TILE;
    const int tx = tid & 7, ty = tid >> 3;       // 8 x-groups (4 px each) x 32 rows
    const int oy  = y0 + ty;
    const int ox0 = x0 + tx * 4;

    const float* xb = x + (size_t)b * (Himg * Wimg * Cn);

    float acc[12];                                // [px*3 + c]
#pragma unroll
    for (int k = 0; k < 12; ++k) acc[k] = 0.0f;

    const bool border = (x0 < 15) || (x0 + TILE + 16 > Wimg) ||
                        (y0 < 15) || (y0 + TILE + 16 > Himg);

    if (!border) {
        // all reads in-bounds: base voffset + uniform tap offset, 3x dwordx4
        const int base_off = (oy * Wimg + ox0) * (int)(Cn * sizeof(float));
        for (int i = 0; i < n; ++i) {
            const int vo = base_off + s_voff[i];   // >= 0 for interior blocks
            const char* p = (const char*)xb + vo;
            const v4 f0 = *(const v4*)(p);
            const v4 f1 = *(const v4*)(p + 16);
            const v4 f2 = *(const v4*)(p + 32);
            acc[0] += f0.x; acc[1] += f0.y; acc[2]  += f0.z; acc[3]  += f0.w;
            acc[4] += f1.x; acc[5] += f1.y; acc[6]  += f1.z; acc[7]  += f1.w;
            acc[8] += f2.x; acc[9] += f2.y; acc[10] += f2.z; acc[11] += f2.w;
        }
    } else {
        // branchless masked path (select offset to 0 when OOB, fma by 0/1 mask)
        for (int i = 0; i < n; ++i) {
            const int yy  = oy + s_dky[i];
            const int xx0 = ox0 + s_dkx[i];
            const bool rowok  = (unsigned)yy < (unsigned)Himg;
            const int rowbase = yy * Wimg;
#pragma unroll
            for (int j = 0; j < 4; ++j) {
                const int  xx = xx0 + j;
                const bool ok = rowok & ((unsigned)xx < (unsigned)Wimg);
                const int off = ok ? (rowbase + xx) * (int)(Cn * sizeof(float)) : 0;
                const float* p = (const float*)((const char*)xb + off);
                const float m  = ok ? 1.0f : 0.0f;
                acc[3 * j + 0] += m * p[0];
                acc[3 * j + 1] += m * p[1];
                acc[3 * j + 2] += m * p[2];
            }
        }
    }

    float r[12];
#pragma unroll
    for (int k = 0; k < 12; ++k) r[k] = acc[k] * w;

    float* o = out + ((size_t)(b * Himg + oy) * Wimg + ox0) * Cn;
    *(v4*)(o)     = v4{r[0], r[1], r[2],  r[3]};
    *(v4*)(o + 4) = v4{r[4], r[5], r[6],  r[7]};
    *(v4*)(o + 8) = v4{r[8], r[9], r[10], r[11]};
}

}  // namespace

extern "C" void kernel_launch(void* const* d_in, const int* in_sizes, int n_in,
                              void* d_out, int out_size, void* d_ws, size_t ws_size,
                              hipStream_t stream) {
    const float* x   = (const float*)d_in[0];
    const float* tbl = (const float*)d_in[1];
    const int*   amt = (const int*)d_in[2];
    const int*   ang = (const int*)d_in[3];
    float*       out = (float*)d_out;
    int*         ws  = (int*)d_ws;

    const int B = in_sizes[2];  // 128
    build_taps<<<B, 64, 0, stream>>>(tbl, amt, ang, ws);
    dim3 grid(Wimg / TILE, Himg / TILE, B);
    blur_conv<<<grid, 256, 0, stream>>>(x, ws, out);
}

// Round 4
// 232.855 us; speedup vs baseline: 1.1786x; 1.0004x over previous
//
#include <hip/hip_runtime.h>
#include <math.h>

namespace {

constexpr int Himg = 224, Wimg = 224, Cn = 3, Kk = 32;
constexpr int MAXT = 64;
constexpr int WSTRIDE = 512;            // ints per image in tap workspace
constexpr int IMG_F  = Himg * Wimg * Cn;       // 150528 floats per image
// padded image: 255 rows (15 top + 224 + 16 bottom), 256-px rows (16 left pad)
constexpr int PAD_ROW_F  = 256 * Cn;           // 768 floats per padded row
constexpr int PAD_ROW_B  = PAD_ROW_F * 4;      // 3072 B
constexpr int PAD_ROWS   = 255;
constexpr int PAD_IMG_F  = PAD_ROWS * PAD_ROW_F;   // 195840
constexpr size_t TAPS_BYTES = 128 * WSTRIDE * sizeof(int);  // 256 KiB

typedef float v4  __attribute__((ext_vector_type(4), aligned(4)));
typedef float v4a __attribute__((ext_vector_type(4), aligned(16)));

// ---------------- pre-pass: one tap list per image ----------------
__global__ __launch_bounds__(64)
void build_taps(const float* __restrict__ tbl,
                const int* __restrict__ amt,
                const int* __restrict__ ang,
                int* __restrict__ ws)
{
    const int b   = blockIdx.x;
    const int tid = threadIdx.x;

    __shared__ int   s_cnt;
    __shared__ float s_w;
    __shared__ int   s_dky[MAXT], s_dkx[MAXT], s_voff[MAXT], s_poff[MAXT];

    if (tid == 0) { s_cnt = 0; s_w = 0.0f; }
    __syncthreads();

    const int a = amt[b];
    // reference-exact numerics (verified absmax 0.0039 in R1-R3)
    const float  rad = (float)ang[b] * (float)(M_PI / 180.0);
    const double rd  = (double)rad;
    const float  cth = (float)cos(rd);
    const float  sth = (float)sin(rd);
    const float  e   = 31.0f;
    const float xoff = __fmul_rn(__fsub_rn(e, __fsub_rn(__fmul_rn(cth, e), __fmul_rn(sth, e))), 0.5f);
    const float yoff = __fmul_rn(__fsub_rn(e, __fadd_rn(__fmul_rn(sth, e), __fmul_rn(cth, e))), 0.5f);

    for (int p = tid; p < Kk * Kk; p += 64) {
        const int   ky = p >> 5, kx = p & 31;
        const float xf = (float)kx, yf = (float)ky;
        const float sx = __fadd_rn(__fsub_rn(__fmul_rn(cth, xf), __fmul_rn(sth, yf)), xoff);
        const float sy = __fadd_rn(__fadd_rn(__fmul_rn(sth, xf), __fmul_rn(cth, yf)), yoff);
        const int ix = (int)rintf(sx);   // round-half-even == jnp.round
        const int iy = (int)rintf(sy);
        if (ix >= 0 && ix < Kk && iy >= 0 && iy < Kk) {
            const float v = tbl[((a * Kk + iy) * Kk + ix) * Cn];
            if (v != 0.0f) {
                const int idx = atomicAdd(&s_cnt, 1);
                if (idx < MAXT) {
                    const int dky = ky - 15, dkx = kx - 15;
                    s_dky[idx]  = dky;
                    s_dkx[idx]  = dkx;
                    s_voff[idx] = (dky * Wimg + dkx) * (int)(Cn * sizeof(float));
                    s_poff[idx] = dky * PAD_ROW_B + dkx * (int)(Cn * sizeof(float));
                    s_w = v;                 // benign race: all writers store 1/size
                }
            }
        }
    }
    __syncthreads();

    const int n = min(s_cnt, MAXT);
    int* wsb = ws + b * WSTRIDE;
    if (tid == 0) { wsb[0] = n; wsb[1] = __float_as_int(s_w); }
    for (int i = tid; i < n; i += 64) {
        wsb[2 + i]            = s_dky[i];
        wsb[2 + MAXT + i]     = s_dkx[i];
        wsb[2 + 2 * MAXT + i] = s_voff[i];
        wsb[2 + 3 * MAXT + i] = s_poff[i];
    }
}

// ---------------- pad pass: zero-padded, 256-px-stride images ----------------
// dst float fd in padded row yy maps to src float (yy-15)*672 + fd - 48.
// valid iff yy-15 in [0,224) and fd in [48, 720); both fd bounds are
// multiples of 4 -> whole 16B chunk shares one mask. Fully coalesced.
__global__ __launch_bounds__(256)
void pad_images(const float* __restrict__ x, float* __restrict__ pad)
{
    const int idx = blockIdx.x * 256 + threadIdx.x;    // < 128*48960
    const int b   = idx / (PAD_ROWS * 192);
    const int r   = idx - b * (PAD_ROWS * 192);
    const int yy  = r / 192;
    const int j   = r - yy * 192;
    const int fd0 = j << 2;
    const int ysrc = yy - 15;

    const int o  = ysrc * (Wimg * Cn) + fd0 - 48;
    const int oc = min(max(o, 0), IMG_F - 4);
    const v4a v  = *(const v4a*)(x + (size_t)b * IMG_F + oc);

    const bool ok = ((unsigned)ysrc < (unsigned)Himg) & (fd0 >= 48) & (fd0 < 720);
    const float m = ok ? 1.0f : 0.0f;

    v4a* dp = (v4a*)(pad + (size_t)b * PAD_IMG_F + (size_t)yy * PAD_ROW_F + fd0);
    *dp = v4a{v.x * m, v.y * m, v.z * m, v.w * m};
}

// ---------------- conv in flat float space: 1 contiguous dwordx4 per tap ----------------
__global__ __launch_bounds__(256)
void blur_conv_pad(const float* __restrict__ pad,
                   const int* __restrict__ ws,
                   float* __restrict__ out)
{
    const int b   = blockIdx.y;
    const int tid = threadIdx.x;

    __shared__ int sh[2 + MAXT];
    const int* wsb = ws + b * WSTRIDE;
    if (tid < 2)    sh[tid]     = wsb[tid];
    if (tid < MAXT) sh[2 + tid] = wsb[2 + 3 * MAXT + tid];   // padded-space offsets
    __syncthreads();

    const int   n = sh[0];
    const float w = __int_as_float(sh[1]);
    const int* soff = sh + 2;

    const int idx = blockIdx.x * 256 + tid;    // [0, 224*168)
    const int y   = idx / 168;                 // output row
    const int k   = idx - y * 168;             // 16B chunk within row (672 floats = 168 chunks)

    // base of this thread's 4 flat floats in padded space:
    // row y+15, float-in-row 48 + 4k  ->  byte (y+15)*3072 + 16k + 192
    const char* base = (const char*)(pad + (size_t)b * PAD_IMG_F)
                     + (y + 15) * PAD_ROW_B + (k << 4) + 192;

    float a0 = 0.0f, a1 = 0.0f, a2 = 0.0f, a3 = 0.0f;
    int i = 0;
    for (; i + 4 <= n; i += 4) {
        const v4 f0 = *(const v4*)(base + soff[i]);
        const v4 f1 = *(const v4*)(base + soff[i + 1]);
        const v4 f2 = *(const v4*)(base + soff[i + 2]);
        const v4 f3 = *(const v4*)(base + soff[i + 3]);
        a0 += f0.x; a1 += f0.y; a2 += f0.z; a3 += f0.w;
        a0 += f1.x; a1 += f1.y; a2 += f1.z; a3 += f1.w;
        a0 += f2.x; a1 += f2.y; a2 += f2.z; a3 += f2.w;
        a0 += f3.x; a1 += f3.y; a2 += f3.z; a3 += f3.w;
    }
    for (; i < n; ++i) {
        const v4 f = *(const v4*)(base + soff[i]);
        a0 += f.x; a1 += f.y; a2 += f.z; a3 += f.w;
    }

    v4a* o = (v4a*)(out + (size_t)b * IMG_F + (size_t)idx * 4);
    *o = v4a{a0 * w, a1 * w, a2 * w, a3 * w};
}

// ---------------- fallback conv (R3, reads x directly) if ws too small ----------------
constexpr int TILE = 32;
__global__ __launch_bounds__(256)
void blur_conv(const float* __restrict__ x,
               const int* __restrict__ ws,
               float* __restrict__ out)
{
    const int b   = blockIdx.z;
    const int tid = threadIdx.x;

    __shared__ int sh[2 + 3 * MAXT];
    const int* wsb = ws + b * WSTRIDE;
    if (tid < 2 + 3 * MAXT) sh[tid] = wsb[tid];
    __syncthreads();

    const int   n = sh[0];
    const float w = __int_as_float(sh[1]);
    const int* s_dky  = sh + 2;
    const int* s_dkx  = sh + 2 + MAXT;
    const int* s_voff = sh + 2 + 2 * MAXT;

    const int x0 = blockIdx.x * TILE, y0 = blockIdx.y * TILE;
    const int tx = tid & 7, ty = tid >> 3;
    const int oy  = y0 + ty;
    const int ox0 = x0 + tx * 4;

    const float* xb = x + (size_t)b * IMG_F;

    float acc[12];
#pragma unroll
    for (int q = 0; q < 12; ++q) acc[q] = 0.0f;

    const bool border = (x0 < 15) || (x0 + TILE + 16 > Wimg) ||
                        (y0 < 15) || (y0 + TILE + 16 > Himg);

    if (!border) {
        const int base_off = (oy * Wimg + ox0) * (int)(Cn * sizeof(float));
        for (int i = 0; i < n; ++i) {
            const char* p = (const char*)xb + (base_off + s_voff[i]);
            const v4 f0 = *(const v4*)(p);
            const v4 f1 = *(const v4*)(p + 16);
            const v4 f2 = *(const v4*)(p + 32);
            acc[0] += f0.x; acc[1] += f0.y; acc[2]  += f0.z; acc[3]  += f0.w;
            acc[4] += f1.x; acc[5] += f1.y; acc[6]  += f1.z; acc[7]  += f1.w;
            acc[8] += f2.x; acc[9] += f2.y; acc[10] += f2.z; acc[11] += f2.w;
        }
    } else {
        for (int i = 0; i < n; ++i) {
            const int yy  = oy + s_dky[i];
            const int xx0 = ox0 + s_dkx[i];
            const bool rowok  = (unsigned)yy < (unsigned)Himg;
            const int rowbase = yy * Wimg;
#pragma unroll
            for (int j = 0; j < 4; ++j) {
                const int  xx = xx0 + j;
                const bool ok = rowok & ((unsigned)xx < (unsigned)Wimg);
                const int off = ok ? (rowbase + xx) * (int)(Cn * sizeof(float)) : 0;
                const float* p = (const float*)((const char*)xb + off);
                const float m  = ok ? 1.0f : 0.0f;
                acc[3 * j + 0] += m * p[0];
                acc[3 * j + 1] += m * p[1];
                acc[3 * j + 2] += m * p[2];
            }
        }
    }

    float r[12];
#pragma unroll
    for (int q = 0; q < 12; ++q) r[q] = acc[q] * w;

    float* o = out + ((size_t)(b * Himg + oy) * Wimg + ox0) * Cn;
    *(v4*)(o)     = v4{r[0], r[1], r[2],  r[3]};
    *(v4*)(o + 4) = v4{r[4], r[5], r[6],  r[7]};
    *(v4*)(o + 8) = v4{r[8], r[9], r[10], r[11]};
}

}  // namespace

extern "C" void kernel_launch(void* const* d_in, const int* in_sizes, int n_in,
                              void* d_out, int out_size, void* d_ws, size_t ws_size,
                              hipStream_t stream) {
    const float* x   = (const float*)d_in[0];
    const float* tbl = (const float*)d_in[1];
    const int*   amt = (const int*)d_in[2];
    const int*   ang = (const int*)d_in[3];
    float*       out = (float*)d_out;
    int*         ws  = (int*)d_ws;

    const int B = in_sizes[2];  // 128

    build_taps<<<B, 64, 0, stream>>>(tbl, amt, ang, ws);

    const size_t need = TAPS_BYTES + (size_t)B * PAD_IMG_F * sizeof(float);
    if (ws_size >= need) {
        float* pad = (float*)((char*)d_ws + TAPS_BYTES);
        const int pad_blocks = B * PAD_ROWS * 192 / 256;            // 24480
        pad_images<<<pad_blocks, 256, 0, stream>>>(x, pad);
        dim3 grid(Himg * 168 / 256, B);                             // (147, 128)
        blur_conv_pad<<<grid, 256, 0, stream>>>(pad, ws, out);
    } else {
        dim3 grid(Wimg / TILE, Himg / TILE, B);
        blur_conv<<<grid, 256, 0, stream>>>(x, ws, out);
    }
}